// Round 9
// baseline (77.307 us; speedup 1.0000x reference)
//
#include <hip/hip_runtime.h>
#include <hip/hip_bf16.h>

#define ALPHA 0.2f
static __device__ __forceinline__ float lrel(float x) { return fmaxf(x, ALPHA * x); }

typedef __attribute__((ext_vector_type(8))) short bf16x8;
typedef __attribute__((ext_vector_type(4))) float f32x4;

union FragU { bf16x8 v; unsigned int u[4]; uint4 q; };

// pack two f32 -> one dword of 2 bf16 (RNE) via the HW instruction
static __device__ __forceinline__ unsigned int pk2(float a, float b) {
    unsigned int r;
    asm("v_cvt_pk_bf16_f32 %0, %1, %2" : "=v"(r) : "v"(a), "v"(b));
    return r;
}
// lrelu both, then pack to bf16 pair
static __device__ __forceinline__ unsigned int cvl2(float a, float b) {
    return pk2(lrel(a), lrel(b));
}
// f32 -> bf16 (RNE) scalar
static __device__ __forceinline__ unsigned short f2bf(float x) {
    union { float f; unsigned int u; } c;
    c.f = x;
    unsigned int r = c.u + 0x7FFFu + ((c.u >> 16) & 1u);
    return (unsigned short)(r >> 16);
}
// pi permutation on 64 features: slot(16nf+4a+r) -> 32(nf>>1)+8a+4(nf&1)+r
static __device__ __forceinline__ int pi64(int s) {
    return 32 * ((s >> 4) >> 1) + 8 * ((s >> 2) & 3) + 4 * ((s >> 4) & 1) + (s & 3);
}

// ---------------- Kernel 1: Upi = pi(x @ W0top + b0), x_bf, weight fragments ----------------
__global__ __launch_bounds__(256) void k_uv(
    const float* __restrict__ x, const float* __restrict__ W0, const float* __restrict__ b0,
    const float* __restrict__ W1, const float* __restrict__ W2,
    float* __restrict__ Upi, unsigned short* __restrict__ xbf, unsigned int* __restrict__ WF)
{
    if (blockIdx.x == 1024) {
        const int t = threadIdx.x;
        const int l = t & 63, part = t >> 6;
        const int lo = l & 15, g = l >> 4;
        for (int ff = part; ff < 20; ff += 4) {
            unsigned int o[4];
            if (ff < 4) {
                const int nf = ff;
                const int pc = 32 * (nf >> 1) + 8 * (lo >> 2) + 4 * (nf & 1) + (lo & 3);
#pragma unroll
                for (int uq = 0; uq < 4; ++uq) {
                    const int k0 = 8 * g + 2 * uq;
                    o[uq] = pk2(W0[(32 + k0) * 64 + pc], W0[(33 + k0) * 64 + pc]);
                }
            } else if (ff < 12) {
                const int s = (ff - 4) >> 2, nf = (ff - 4) & 3;
                const int pc = 32 * (nf >> 1) + 8 * (lo >> 2) + 4 * (nf & 1) + (lo & 3);
#pragma unroll
                for (int uq = 0; uq < 4; ++uq) {
                    const int k0 = 32 * s + 8 * g + 2 * uq;
                    o[uq] = pk2(W1[k0 * 64 + pc], W1[(k0 + 1) * 64 + pc]);
                }
            } else {
                const int s = (ff - 12) >> 2, nf = (ff - 12) & 3;
                const int c2 = 16 * nf + lo;
#pragma unroll
                for (int uq = 0; uq < 4; ++uq) {
                    const int k0 = 32 * s + 8 * g + 2 * uq;
                    o[uq] = pk2(W2[k0 * 64 + c2], W2[(k0 + 1) * 64 + c2]);
                }
            }
            *(uint4*)(WF + (ff * 64 + l) * 4) = make_uint4(o[0], o[1], o[2], o[3]);
        }
        return;
    }
    const int idx = blockIdx.x * 256 + threadIdx.x;
    const int n = idx >> 6;
    const int slot = idx & 63;
    const int f = pi64(slot);
    const float* xr = x + n * 32;
    float u = b0[f];
#pragma unroll
    for (int i = 0; i < 32; ++i) u += xr[i] * W0[i * 64 + f];
    Upi[idx] = u;
    if (slot < 32) xbf[n * 32 + slot] = f2bf(xr[slot]);
}

// ---------------- Kernel 2: edge MLP (all 3 layers on MFMA) + sum over j ----------------
// DUAL CHAINS per wave: each wave owns 2 nodes (i and i+4, same batch b), sharing
// the xj fragment and all weight fragments. Chain B's MFMAs issue during chain A's
// pack/agg VALU phases (intra-wave dovetail). W1/W2 fragments streamed from LDS.
// grid: 512 blocks = 8(b) x 64(ig); 4 waves/block.
__global__ __launch_bounds__(256, 2) void k_edge(
    const float* __restrict__ Upi, const unsigned short* __restrict__ xbf,
    const unsigned int* __restrict__ WF,
    const float* __restrict__ b1, const float* __restrict__ b2,
    float* __restrict__ AGG)
{
    __shared__ uint4 wlds[1024];  // frags 4..19 of WF: [0..7]=w1f, [8..15]=w2f
    const int tid = threadIdx.x;
    const int w = tid >> 6, l = tid & 63;
    const int lo = l & 15, g = l >> 4;
    const int bid = blockIdx.x;
    const int b = bid >> 6, ig = bid & 63;
    const int nodeA = b * 512 + ig * 8 + w;
    const int nodeB = nodeA + 4;

    // ---- stage W1/W2 fragments into LDS (once per block)
    for (int idx = tid; idx < 1024; idx += 256)
        wlds[idx] = ((const uint4*)WF)[256 + idx];

    // ---- W0bot fragments in registers (shared by both chains)
    FragU w0f[4];
    const uint4* wp = (const uint4*)WF;
#pragma unroll
    for (int nf = 0; nf < 4; ++nf) w0f[nf].q = wp[nf * 64 + l];

    // ---- per-chain GEMM0 C-init (Upi broadcast) + shared bias C-inits
    f32x4 uA[4], uB[4], b1f[4], b2f[4];
#pragma unroll
    for (int nf = 0; nf < 4; ++nf) {
        const float4 ta = *(const float4*)(Upi + nodeA * 64 + nf * 16 + 4 * g);
        const float4 tb = *(const float4*)(Upi + nodeB * 64 + nf * 16 + 4 * g);
        uA[nf] = (f32x4){ta.x, ta.y, ta.z, ta.w};
        uB[nf] = (f32x4){tb.x, tb.y, tb.z, tb.w};
        const float4 t1 = *(const float4*)(b1 + 32 * (nf >> 1) + 8 * g + 4 * (nf & 1));
        const float4 t2 = *(const float4*)(b2 + 16 * nf + 4 * g);
        b1f[nf] = (f32x4){t1.x, t1.y, t1.z, t1.w};
        b2f[nf] = (f32x4){t2.x, t2.y, t2.z, t2.w};
    }

    const unsigned short* xb = xbf + b * 512 * 32;
    FragU xj;
    xj.q = *(const uint4*)(xb + lo * 32 + 8 * g);  // tile 0 (shared by both chains)

    float aggA[4][4], aggB[4][4];
#pragma unroll
    for (int nf = 0; nf < 4; ++nf)
#pragma unroll
        for (int r = 0; r < 4; ++r) { aggA[nf][r] = 0.f; aggB[nf][r] = 0.f; }

    __syncthreads();

#pragma unroll 1
    for (int k = 0; k < 32; ++k) {
        // opaque zero: defeats LICM on the LDS weight reads
        int widx = 0;
        asm volatile("" : "+v"(widx));

        // prefetch next tile's xj (shared)
        const int jn = ((k + 1) & 31) * 16;
        FragU xjn;
        xjn.q = *(const uint4*)(xb + (jn + lo) * 32 + 8 * g);

        // ---- GEMM0 both chains (C = per-i Upi broadcast)
        f32x4 a0A[4], a0B[4];
#pragma unroll
        for (int nf = 0; nf < 4; ++nf) {
            a0A[nf] = __builtin_amdgcn_mfma_f32_16x16x32_bf16(w0f[nf].v, xj.v, uA[nf], 0, 0, 0);
            a0B[nf] = __builtin_amdgcn_mfma_f32_16x16x32_bf16(w0f[nf].v, xj.v, uB[nf], 0, 0, 0);
        }

        // ---- chain A: pack q (overlaps chain B's GEMM0 in flight)
        FragU qA0, qA1;
        qA0.u[0] = cvl2(a0A[0][0], a0A[0][1]);
        qA0.u[1] = cvl2(a0A[0][2], a0A[0][3]);
        qA0.u[2] = cvl2(a0A[1][0], a0A[1][1]);
        qA0.u[3] = cvl2(a0A[1][2], a0A[1][3]);
        qA1.u[0] = cvl2(a0A[2][0], a0A[2][1]);
        qA1.u[1] = cvl2(a0A[2][2], a0A[2][3]);
        qA1.u[2] = cvl2(a0A[3][0], a0A[3][1]);
        qA1.u[3] = cvl2(a0A[3][2], a0A[3][3]);

        // ---- chain A: GEMM1
        f32x4 a1A[4];
#pragma unroll
        for (int nf = 0; nf < 4; ++nf) {
            FragU wa, wb;
            wa.q = wlds[widx + nf * 64 + l];
            wb.q = wlds[widx + (4 + nf) * 64 + l];
            a1A[nf] = __builtin_amdgcn_mfma_f32_16x16x32_bf16(wa.v, qA0.v, b1f[nf], 0, 0, 0);
            a1A[nf] = __builtin_amdgcn_mfma_f32_16x16x32_bf16(wb.v, qA1.v, a1A[nf], 0, 0, 0);
        }

        // ---- chain B: pack q (overlaps chain A's GEMM1)
        FragU qB0, qB1;
        qB0.u[0] = cvl2(a0B[0][0], a0B[0][1]);
        qB0.u[1] = cvl2(a0B[0][2], a0B[0][3]);
        qB0.u[2] = cvl2(a0B[1][0], a0B[1][1]);
        qB0.u[3] = cvl2(a0B[1][2], a0B[1][3]);
        qB1.u[0] = cvl2(a0B[2][0], a0B[2][1]);
        qB1.u[1] = cvl2(a0B[2][2], a0B[2][3]);
        qB1.u[2] = cvl2(a0B[3][0], a0B[3][1]);
        qB1.u[3] = cvl2(a0B[3][2], a0B[3][3]);

        // ---- chain B: GEMM1
        f32x4 a1B[4];
#pragma unroll
        for (int nf = 0; nf < 4; ++nf) {
            FragU wa, wb;
            wa.q = wlds[widx + nf * 64 + l];
            wb.q = wlds[widx + (4 + nf) * 64 + l];
            a1B[nf] = __builtin_amdgcn_mfma_f32_16x16x32_bf16(wa.v, qB0.v, b1f[nf], 0, 0, 0);
            a1B[nf] = __builtin_amdgcn_mfma_f32_16x16x32_bf16(wb.v, qB1.v, a1B[nf], 0, 0, 0);
        }

        // ---- chain A: pack p (overlaps chain B's GEMM1)
        FragU pA0, pA1;
        pA0.u[0] = cvl2(a1A[0][0], a1A[0][1]);
        pA0.u[1] = cvl2(a1A[0][2], a1A[0][3]);
        pA0.u[2] = cvl2(a1A[1][0], a1A[1][1]);
        pA0.u[3] = cvl2(a1A[1][2], a1A[1][3]);
        pA1.u[0] = cvl2(a1A[2][0], a1A[2][1]);
        pA1.u[1] = cvl2(a1A[2][2], a1A[2][3]);
        pA1.u[2] = cvl2(a1A[3][0], a1A[3][1]);
        pA1.u[3] = cvl2(a1A[3][2], a1A[3][3]);

        // ---- chain A: GEMM2
        f32x4 a2A[4];
#pragma unroll
        for (int nf = 0; nf < 4; ++nf) {
            FragU wa, wb;
            wa.q = wlds[widx + (8 + nf) * 64 + l];
            wb.q = wlds[widx + (12 + nf) * 64 + l];
            a2A[nf] = __builtin_amdgcn_mfma_f32_16x16x32_bf16(wa.v, pA0.v, b2f[nf], 0, 0, 0);
            a2A[nf] = __builtin_amdgcn_mfma_f32_16x16x32_bf16(wb.v, pA1.v, a2A[nf], 0, 0, 0);
        }

        // ---- chain B: pack p (overlaps chain A's GEMM2)
        FragU pB0, pB1;
        pB0.u[0] = cvl2(a1B[0][0], a1B[0][1]);
        pB0.u[1] = cvl2(a1B[0][2], a1B[0][3]);
        pB0.u[2] = cvl2(a1B[1][0], a1B[1][1]);
        pB0.u[3] = cvl2(a1B[1][2], a1B[1][3]);
        pB1.u[0] = cvl2(a1B[2][0], a1B[2][1]);
        pB1.u[1] = cvl2(a1B[2][2], a1B[2][3]);
        pB1.u[2] = cvl2(a1B[3][0], a1B[3][1]);
        pB1.u[3] = cvl2(a1B[3][2], a1B[3][3]);

        // ---- chain B: GEMM2
        f32x4 a2B[4];
#pragma unroll
        for (int nf = 0; nf < 4; ++nf) {
            FragU wa, wb;
            wa.q = wlds[widx + (8 + nf) * 64 + l];
            wb.q = wlds[widx + (12 + nf) * 64 + l];
            a2B[nf] = __builtin_amdgcn_mfma_f32_16x16x32_bf16(wa.v, pB0.v, b2f[nf], 0, 0, 0);
            a2B[nf] = __builtin_amdgcn_mfma_f32_16x16x32_bf16(wb.v, pB1.v, a2B[nf], 0, 0, 0);
        }

        // ---- agg chain A (overlaps chain B's GEMM2), then agg chain B
#pragma unroll
        for (int nf = 0; nf < 4; ++nf)
#pragma unroll
            for (int r = 0; r < 4; ++r) aggA[nf][r] += lrel(a2A[nf][r]);
#pragma unroll
        for (int nf = 0; nf < 4; ++nf)
#pragma unroll
            for (int r = 0; r < 4; ++r) aggB[nf][r] += lrel(a2B[nf][r]);

        xj = xjn;
    }

    // ---- reduce over the 16 edge-lanes (lo); lanes lo==0 hold full sums
#pragma unroll
    for (int nf = 0; nf < 4; ++nf)
#pragma unroll
        for (int r = 0; r < 4; ++r) {
            float va = aggA[nf][r];
            va += __shfl_xor(va, 1);
            va += __shfl_xor(va, 2);
            va += __shfl_xor(va, 4);
            va += __shfl_xor(va, 8);
            aggA[nf][r] = va;
            float vb = aggB[nf][r];
            vb += __shfl_xor(vb, 1);
            vb += __shfl_xor(vb, 2);
            vb += __shfl_xor(vb, 4);
            vb += __shfl_xor(vb, 8);
            aggB[nf][r] = vb;
        }
    if (lo == 0) {
#pragma unroll
        for (int nf = 0; nf < 4; ++nf) {
            float4 oa = {aggA[nf][0], aggA[nf][1], aggA[nf][2], aggA[nf][3]};
            *(float4*)(AGG + nodeA * 64 + 16 * nf + 4 * g) = oa;
            float4 ob = {aggB[nf][0], aggB[nf][1], aggB[nf][2], aggB[nf][3]};
            *(float4*)(AGG + nodeB * 64 + 16 * nf + 4 * g) = ob;
        }
    }
}

// ---------------- Kernel 3: node MLP fn: [agg, x] -> 128 -> 128 -> 32 ----------------
__global__ __launch_bounds__(256) void k_fn(
    const float* __restrict__ AGG, const float* __restrict__ x,
    const float* __restrict__ W0, const float* __restrict__ b0,
    const float* __restrict__ W1, const float* __restrict__ b1,
    const float* __restrict__ W2, const float* __restrict__ b2,
    float* __restrict__ out)
{
    __shared__ float in96T[96][8];
    __shared__ float h1T[128][8];
    __shared__ float h2T[128][8];
    const int t = threadIdx.x;
    const int half = t >> 7, f = t & 127;
    const int node0 = blockIdx.x * 8;

    for (int idx = t; idx < 768; idx += 256) {
        int nn = idx & 7, k = idx >> 3;
        in96T[k][nn] = (k < 64) ? AGG[(node0 + nn) * 64 + k]
                                : x[(node0 + nn) * 32 + (k - 64)];
    }
    __syncthreads();

    {
        float a0 = b0[f], a1 = a0, a2 = a0, a3 = a0;
#pragma unroll 4
        for (int k = 0; k < 96; ++k) {
            const float4 iv = *(const float4*)(&in96T[k][4 * half]);
            const float wv = W0[k * 128 + f];
            a0 += iv.x * wv; a1 += iv.y * wv; a2 += iv.z * wv; a3 += iv.w * wv;
        }
        float4 o = {lrel(a0), lrel(a1), lrel(a2), lrel(a3)};
        *(float4*)(&h1T[f][4 * half]) = o;
    }
    __syncthreads();

    {
        float a0 = b1[f], a1 = a0, a2 = a0, a3 = a0;
#pragma unroll 4
        for (int k = 0; k < 128; ++k) {
            const float4 iv = *(const float4*)(&h1T[k][4 * half]);
            const float wv = W1[k * 128 + f];
            a0 += iv.x * wv; a1 += iv.y * wv; a2 += iv.z * wv; a3 += iv.w * wv;
        }
        float4 o = {lrel(a0), lrel(a1), lrel(a2), lrel(a3)};
        *(float4*)(&h2T[f][4 * half]) = o;
    }
    __syncthreads();

    {
        const int nn = t >> 5, fo = t & 31;
        float a = b2[fo];
#pragma unroll 4
        for (int k = 0; k < 128; ++k) a += h2T[k][nn] * W2[k * 32 + fo];
        out[(node0 + nn) * 32 + fo] = a;
    }
}

extern "C" void kernel_launch(void* const* d_in, const int* in_sizes, int n_in,
                              void* d_out, int out_size, void* d_ws, size_t ws_size,
                              hipStream_t stream)
{
    const float* x    = (const float*)d_in[0];
    const float* feW0 = (const float*)d_in[1];
    const float* feb0 = (const float*)d_in[2];
    const float* feW1 = (const float*)d_in[3];
    const float* feb1 = (const float*)d_in[4];
    const float* feW2 = (const float*)d_in[5];
    const float* feb2 = (const float*)d_in[6];
    const float* fnW0 = (const float*)d_in[7];
    const float* fnb0 = (const float*)d_in[8];
    const float* fnW1 = (const float*)d_in[9];
    const float* fnb1 = (const float*)d_in[10];
    const float* fnW2 = (const float*)d_in[11];
    const float* fnb2 = (const float*)d_in[12];
    float* out = (float*)d_out;

    // workspace: Upi (1MB) | AGG (1MB) | xbf (256KB) | WF (20KB)
    float* Upi = (float*)d_ws;
    float* AGG = Upi + 262144;
    unsigned short* xbf = (unsigned short*)(AGG + 262144);
    unsigned int* WF = (unsigned int*)(xbf + 131072);

    hipLaunchKernelGGL(k_uv,   dim3(1025), dim3(256), 0, stream, x, feW0, feb0, feW1, feW2, Upi, xbf, WF);
    hipLaunchKernelGGL(k_edge, dim3(512),  dim3(256), 0, stream, Upi, xbf, WF, feb1, feb2, AGG);
    hipLaunchKernelGGL(k_fn,   dim3(512),  dim3(256), 0, stream, AGG, x, fnW0, fnb0, fnW1, fnb1, fnW2, fnb2, out);
}